// Round 17
// baseline (262.008 us; speedup 1.0000x reference)
//
#include <hip/hip_runtime.h>
#include <hip/hip_bf16.h>
#include <math.h>

#define NN 16384     // nodes
#define NE 262144    // edges
#define KDIM1 480
#define DHID 256
#define DOUT3 128
#define NG 256       // graphs

typedef short bf16x8 __attribute__((ext_vector_type(8)));
typedef float f32x4 __attribute__((ext_vector_type(4)));

#define LOG2E 1.44269504088896340736f

__device__ __forceinline__ unsigned short f2bf(float f) {
  unsigned u = __float_as_uint(f);
  unsigned r = (u + 0x7fffu + ((u >> 16) & 1u)) >> 16;
  return (unsigned short)r;
}
__device__ __forceinline__ float bf2f(unsigned short u) {
  return __uint_as_float((unsigned)u << 16);
}

__device__ __forceinline__ void gload_lds16(const void* g, void* l) {
  __builtin_amdgcn_global_load_lds((const __attribute__((address_space(1))) void*)g,
                                   (__attribute__((address_space(3))) void*)l,
                                   16, 0, 0);
}

__device__ __forceinline__ int lower_bound_i(const int* arr, int n, int val) {
  int lo = 0, hi = n;
  while (lo < hi) {
    int mid = (lo + hi) >> 1;
    if (arr[mid] < val) lo = mid + 1; else hi = mid;
  }
  return lo;
}

// ============================ CSR build ============================

__global__ __launch_bounds__(256) void k_edge_count(const int* __restrict__ ei,
                                                    const float* __restrict__ ea,
                                                    int* __restrict__ deg,
                                                    float* __restrict__ easum) {
  int e = blockIdx.x * 256 + threadIdx.x;
  if (e >= NE) return;
  int d = ei[NE + e];
  atomicAdd(&deg[d], 1);
  atomicAdd(&easum[d], ea[e]);
}

// scan + loop_ea finalize + per-graph inverse counts (threads t<NG)
__global__ __launch_bounds__(1024) void k_scan(const int* __restrict__ deg,
                                               float* __restrict__ easum,
                                               int* __restrict__ offs,
                                               int* __restrict__ cursor,
                                               const int* __restrict__ bat,
                                               float* __restrict__ ginv) {
  __shared__ int sums[1024];
  int t = threadIdx.x;
  int base = t * 16;
  int local[16];
  int s = 0;
#pragma unroll
  for (int i = 0; i < 16; ++i) { local[i] = deg[base + i]; s += local[i]; }
  sums[t] = s;
  __syncthreads();
  for (int d = 1; d < 1024; d <<= 1) {
    int v = (t >= d) ? sums[t - d] : 0;
    __syncthreads();
    sums[t] += v;
    __syncthreads();
  }
  int prefix = (t == 0) ? 0 : sums[t - 1];
#pragma unroll
  for (int i = 0; i < 16; ++i) {
    offs[base + i] = prefix;
    cursor[base + i] = prefix;
    prefix += local[i];
  }
  if (t == 1023) offs[NN] = prefix;
#pragma unroll
  for (int i = 0; i < 16; ++i) {
    easum[base + i] = easum[base + i] / fmaxf((float)local[i], 1.f);
  }
  if (t < NG) {
    int lo = lower_bound_i(bat, NN, t);
    int hi = lower_bound_i(bat, NN, t + 1);
    ginv[t] = 1.f / fmaxf((float)(hi - lo), 1.f);
  }
}

__global__ __launch_bounds__(256) void k_fill_csr(const int* __restrict__ ei,
                                                  const float* __restrict__ ea,
                                                  int* __restrict__ cursor,
                                                  int* __restrict__ csr_src,
                                                  float* __restrict__ csr_ea) {
  int e = blockIdx.x * 256 + threadIdx.x;
  if (e >= NE) return;
  int s = ei[e];
  int d = ei[NE + e];
  int pos = atomicAdd(&cursor[d], 1);
  csr_src[pos] = s;
  csr_ea[pos] = ea[e];
}

// ============================ merged prep: x->bf16 + all weight transposes ============================
// seg0: x convert; seg1: Wc1e=[Wl1|Wr1|Wres] (N=768); seg2: Wc2; seg3: Wc3.

#define PREP_S0 (NN * KDIM1 / 4)
#define PREP_S1 (3 * DHID * KDIM1)
#define PREP_S2 (2 * DHID * DHID)
#define PREP_S3 (2 * DOUT3 * DHID)
#define PREP_TOTAL (PREP_S0 + PREP_S1 + PREP_S2 + PREP_S3)

__global__ __launch_bounds__(256) void k_prep(
    const float* __restrict__ x,
    const float* __restrict__ Wl1, const float* __restrict__ Wr1,
    const float* __restrict__ Wres,
    const float* __restrict__ Wl2, const float* __restrict__ Wr2,
    const float* __restrict__ Wl3, const float* __restrict__ Wr3,
    unsigned short* __restrict__ actb0, unsigned short* __restrict__ Wc1e,
    unsigned short* __restrict__ Wc2, unsigned short* __restrict__ Wc3) {
  int idx = blockIdx.x * 256 + threadIdx.x;
  if (idx < PREP_S0) {
    int i = idx * 4;
    float4 v = *(const float4*)&x[i];
    ushort4 o;
    o.x = f2bf(v.x); o.y = f2bf(v.y); o.z = f2bf(v.z); o.w = f2bf(v.w);
    *(ushort4*)&actb0[i] = o;
    return;
  }
  idx -= PREP_S0;
  if (idx < PREP_S1) {
    int n = idx / KDIM1, k = idx % KDIM1;
    float v;
    if (n < DHID)            v = Wl1[(size_t)k * DHID + n];
    else if (n < 2 * DHID)   v = Wr1[(size_t)k * DHID + (n - DHID)];
    else                     v = Wres[(size_t)k * DHID + (n - 2 * DHID)];
    Wc1e[idx] = f2bf(v);
    return;
  }
  idx -= PREP_S1;
  if (idx < PREP_S2) {
    int n = idx / DHID, k = idx % DHID;
    float v = (n < DHID) ? Wl2[(size_t)k * DHID + n] : Wr2[(size_t)k * DHID + (n - DHID)];
    Wc2[idx] = f2bf(v);
    return;
  }
  idx -= PREP_S2;
  if (idx < PREP_S3) {
    int n = idx / DHID, k = idx % DHID;
    float v = (n < DOUT3) ? Wl3[(size_t)k * DOUT3 + n] : Wr3[(size_t)k * DOUT3 + (n - DOUT3)];
    Wc3[idx] = f2bf(v);
  }
}

// ============================ bf16 MFMA GEMM cores ============================
// 128x128 tile, BK=32, 4 waves (2x2), each wave 64x64 = 4x4 16x16 frags.

#define GEMM_CORE128(A_, Bt_, K_)                                                \
  __shared__ short As[128 * 32];                                                 \
  __shared__ short Bs[128 * 32];                                                 \
  int t = threadIdx.x;                                                           \
  int w = t >> 6;                                                                \
  int lane = t & 63;                                                             \
  int bm = blockIdx.y * 128;                                                     \
  int bn = blockIdx.x * 128;                                                     \
  int wr = w >> 1, wc = w & 1;                                                   \
  const short* Ag0 = A_ + (size_t)(bm + w * 16 + (lane >> 2)) * K_ + (lane & 3) * 8;        \
  const short* Ag1 = A_ + (size_t)(bm + 64 + w * 16 + (lane >> 2)) * K_ + (lane & 3) * 8;   \
  const short* Bg0 = Bt_ + (size_t)(bn + w * 16 + (lane >> 2)) * K_ + (lane & 3) * 8;       \
  const short* Bg1 = Bt_ + (size_t)(bn + 64 + w * 16 + (lane >> 2)) * K_ + (lane & 3) * 8;  \
  short* Al0 = &As[w * 16 * 32];                                                 \
  short* Al1 = &As[(64 + w * 16) * 32];                                          \
  short* Bl0 = &Bs[w * 16 * 32];                                                 \
  short* Bl1 = &Bs[(64 + w * 16) * 32];                                          \
  f32x4 acc[4][4] = {};                                                          \
  for (int k0 = 0; k0 < K_; k0 += 32) {                                          \
    gload_lds16(Ag0, Al0);                                                       \
    gload_lds16(Ag1, Al1);                                                       \
    gload_lds16(Bg0, Bl0);                                                       \
    gload_lds16(Bg1, Bl1);                                                       \
    Ag0 += 32; Ag1 += 32; Bg0 += 32; Bg1 += 32;                                  \
    __syncthreads();                                                             \
    bf16x8 af[4], bfv[4];                                                        \
    _Pragma("unroll")                                                            \
    for (int mi = 0; mi < 4; ++mi)                                               \
      af[mi] = *(const bf16x8*)&As[(wr * 64 + mi * 16 + (lane & 15)) * 32 + (lane >> 4) * 8]; \
    _Pragma("unroll")                                                            \
    for (int ni = 0; ni < 4; ++ni)                                               \
      bfv[ni] = *(const bf16x8*)&Bs[(wc * 64 + ni * 16 + (lane & 15)) * 32 + (lane >> 4) * 8]; \
    _Pragma("unroll")                                                            \
    for (int mi = 0; mi < 4; ++mi)                                               \
      _Pragma("unroll")                                                          \
      for (int ni = 0; ni < 4; ++ni)                                             \
        acc[mi][ni] = __builtin_amdgcn_mfma_f32_16x16x32_bf16(af[mi], bfv[ni], acc[mi][ni], 0, 0, 0); \
    __syncthreads();                                                             \
  }                                                                              \
  int col = lane & 15;                                                           \
  int row4 = (lane >> 4) * 4;

// Layer-1 triple: n<NH -> xlb(+bl); n<2NH -> xrb(+br); else -> xres (f32, no bias).
// grid.x = 3*NH/128.
__global__ __launch_bounds__(256) void gemm_lrr(const short* __restrict__ A,
                                                const short* __restrict__ Wt,
                                                const float* __restrict__ bl,
                                                const float* __restrict__ br,
                                                unsigned short* __restrict__ xlb,
                                                unsigned short* __restrict__ xrb,
                                                float* __restrict__ xres,
                                                int K, int NH) {
  GEMM_CORE128(A, Wt, K)
  int seg = bn / NH;            // 0,1,2 (tile never straddles: NH%128==0)
  int cbase = bn - seg * NH;
#pragma unroll
  for (int mi = 0; mi < 4; ++mi) {
#pragma unroll
    for (int ni = 0; ni < 4; ++ni) {
      f32x4 a = acc[mi][ni];
      int gc = cbase + wc * 64 + ni * 16 + col;
      if (seg == 2) {
#pragma unroll
        for (int r = 0; r < 4; ++r) {
          int gr = bm + wr * 64 + mi * 16 + row4 + r;
          xres[(size_t)gr * NH + gc] = a[r];
        }
      } else {
        const float* bias = seg ? br : bl;
        unsigned short* outp = seg ? xrb : xlb;
        float bv = bias[gc];
#pragma unroll
        for (int r = 0; r < 4; ++r) {
          int gr = bm + wr * 64 + mi * 16 + row4 + r;
          outp[(size_t)gr * NH + gc] = f2bf(a[r] + bv);
        }
      }
    }
  }
}

// C left/right split, bf16 outputs. grid.x = 2*NH/128 (NH%128==0).
__global__ __launch_bounds__(256) void gemm_lr(const short* __restrict__ A,
                                               const short* __restrict__ Wt,
                                               const float* __restrict__ bl,
                                               const float* __restrict__ br,
                                               unsigned short* __restrict__ xlb,
                                               unsigned short* __restrict__ xrb,
                                               int K, int NH) {
  GEMM_CORE128(A, Wt, K)
  bool right = (bn >= NH);
  unsigned short* outp = right ? xrb : xlb;
  const float* bias = right ? br : bl;
  int cbase = right ? bn - NH : bn;
#pragma unroll
  for (int mi = 0; mi < 4; ++mi) {
#pragma unroll
    for (int ni = 0; ni < 4; ++ni) {
      f32x4 a = acc[mi][ni];
      int gc = cbase + wc * 64 + ni * 16 + col;
      float bv = bias[gc];
#pragma unroll
      for (int r = 0; r < 4; ++r) {
        int gr = bm + wr * 64 + mi * 16 + row4 + r;
        outp[(size_t)gr * NH + gc] = f2bf(a[r] + bv);
      }
    }
  }
}

// ============================ fused GATv2 + LN (+GELU) (+RES) (+POOL) ============================
// TWO waves per node: wave0 = self-loop + edges [0,h), wave1 = edges [h,cnt)
// starting from (m=-inf,l=0,acc=0). Wave1 publishes state via LDS; wave0 merges
// the two online-softmax states and runs the epilogue. 4-edge unrolled loop
// (r15-proven); exp2-domain softmax; bf16 gather.

template<int D, int H, bool GELU_, bool RES_, bool WF32, bool WBF16, bool POOL>
__global__ __launch_bounds__(256) void gat_fused(
    const unsigned short* __restrict__ xlb, const unsigned short* __restrict__ xrb,
    const float* __restrict__ We, const float* __restrict__ att,
    const float* __restrict__ bo,
    const int* __restrict__ offs, const int* __restrict__ csr_src,
    const float* __restrict__ csr_ea, const float* __restrict__ loop_ea,
    const float* __restrict__ g, const float* __restrict__ bln,
    const float* __restrict__ res,
    float* __restrict__ outf, unsigned short* __restrict__ outb,
    const int* __restrict__ batch, const float* __restrict__ ginv,
    float* __restrict__ outp) {
  constexpr int P = D / 64;
  constexpr int C = D / H;
  constexpr int GROUP = C / P;   // lanes per head
  __shared__ float lsm[4 * 64];
  __shared__ float lsl[4 * 64];
  __shared__ float lsacc[4 * 64 * P];

  int wv = threadIdx.x >> 6;
  int lane = threadIdx.x & 63;
  int gw = blockIdx.x * 4 + wv;       // global wave id
  int n = gw >> 1;                    // 2 waves per node (grid sized exactly)
  int sub = gw & 1;
  int d0 = lane * P;

  float wev[P], attv[P], xrv[P];
  if constexpr (P == 4) {
    *(float4*)wev = *(const float4*)&We[d0];
    *(float4*)attv = *(const float4*)&att[d0];
    ushort4 u = *(const ushort4*)&xrb[(size_t)n * D + d0];
    xrv[0] = bf2f(u.x); xrv[1] = bf2f(u.y); xrv[2] = bf2f(u.z); xrv[3] = bf2f(u.w);
  } else {
    *(float2*)wev = *(const float2*)&We[d0];
    *(float2*)attv = *(const float2*)&att[d0];
    ushort2 u = *(const ushort2*)&xrb[(size_t)n * D + d0];
    xrv[0] = bf2f(u.x); xrv[1] = bf2f(u.y);
  }
#pragma unroll
  for (int p = 0; p < P; ++p) attv[p] *= LOG2E;   // exp2 domain (monotone)

#define GATHER(dst, srcidx)                                                  \
  {                                                                          \
    if constexpr (P == 4) {                                                  \
      ushort4 u_ = *(const ushort4*)&xlb[(size_t)(srcidx) * D + d0];         \
      dst[0] = bf2f(u_.x); dst[1] = bf2f(u_.y);                              \
      dst[2] = bf2f(u_.z); dst[3] = bf2f(u_.w);                              \
    } else {                                                                 \
      ushort2 u_ = *(const ushort2*)&xlb[(size_t)(srcidx) * D + d0];         \
      dst[0] = bf2f(u_.x); dst[1] = bf2f(u_.y);                              \
    }                                                                        \
  }

#define ALPHA(out_, xv_, eav_)                                               \
  {                                                                          \
    float partial_ = 0.f;                                                    \
    _Pragma("unroll")                                                        \
    for (int p = 0; p < P; ++p) {                                            \
      float s_ = xv_[p] + xrv[p] + (eav_) * wev[p];                          \
      s_ = fmaxf(s_, 0.2f * s_);                                             \
      partial_ = fmaf(s_, attv[p], partial_);                                \
    }                                                                        \
    _Pragma("unroll")                                                        \
    for (int w_ = 1; w_ < GROUP; w_ <<= 1) partial_ += __shfl_xor(partial_, w_, 64); \
    out_ = partial_;                                                         \
  }

  float acc[P];
  float m, l;
  int beg = offs[n];
  int cnt = offs[n + 1] - beg;
  int sbeg = __builtin_amdgcn_readfirstlane(beg);
  int scnt = __builtin_amdgcn_readfirstlane(cnt);
  int h = scnt >> 1;                 // wave0: self + [0,h); wave1: [h,scnt)

  int e, eend;
  if (sub == 0) {
    // self-loop prologue
    float xs[P];
    GATHER(xs, n)
    ALPHA(m, xs, loop_ea[n])
    l = 1.f;
#pragma unroll
    for (int p = 0; p < P; ++p) acc[p] = xs[p];
    e = 0; eend = h;
  } else {
    m = -INFINITY; l = 0.f;
#pragma unroll
    for (int p = 0; p < P; ++p) acc[p] = 0.f;
    e = h; eend = scnt;
  }

  for (; e + 4 <= eend; e += 4) {
    int s0 = csr_src[sbeg + e];
    int s1 = csr_src[sbeg + e + 1];
    int s2 = csr_src[sbeg + e + 2];
    int s3 = csr_src[sbeg + e + 3];
    float ea0 = csr_ea[sbeg + e];
    float ea1 = csr_ea[sbeg + e + 1];
    float ea2 = csr_ea[sbeg + e + 2];
    float ea3 = csr_ea[sbeg + e + 3];
    float xv0[P], xv1[P], xv2[P], xv3[P];
    GATHER(xv0, s0)
    GATHER(xv1, s1)
    GATHER(xv2, s2)
    GATHER(xv3, s3)
    float a0, a1, a2, a3;
    ALPHA(a0, xv0, ea0)
    ALPHA(a1, xv1, ea1)
    ALPHA(a2, xv2, ea2)
    ALPHA(a3, xv3, ea3)
    float nm = fmaxf(fmaxf(m, fmaxf(a0, a1)), fmaxf(a2, a3));
    float sc = exp2f(m - nm);
    float pe0 = exp2f(a0 - nm);
    float pe1 = exp2f(a1 - nm);
    float pe2 = exp2f(a2 - nm);
    float pe3 = exp2f(a3 - nm);
    l = fmaf(l, sc, (pe0 + pe1) + (pe2 + pe3));
#pragma unroll
    for (int p = 0; p < P; ++p)
      acc[p] = fmaf(acc[p], sc,
                    fmaf(pe0, xv0[p], fmaf(pe1, xv1[p], fmaf(pe2, xv2[p], pe3 * xv3[p]))));
    m = nm;
  }
  for (; e < eend; ++e) {
    int s0 = csr_src[sbeg + e];
    float ea0 = csr_ea[sbeg + e];
    float xv0[P];
    GATHER(xv0, s0)
    float a0;
    ALPHA(a0, xv0, ea0)
    float nm = fmaxf(m, a0);
    float sc = exp2f(m - nm);
    float pe0 = exp2f(a0 - nm);
    l = fmaf(l, sc, pe0);
#pragma unroll
    for (int p = 0; p < P; ++p) acc[p] = fmaf(acc[p], sc, pe0 * xv0[p]);
    m = nm;
  }
#undef GATHER
#undef ALPHA

  // ---- cross-wave merge ----
  if (sub == 1) {
    int sl = wv * 64 + lane;
    lsm[sl] = m; lsl[sl] = l;
#pragma unroll
    for (int p = 0; p < P; ++p) lsacc[sl * P + p] = acc[p];
  }
  __syncthreads();
  if (sub == 1) return;
  {
    int ps = (wv + 1) * 64 + lane;
    float m1 = lsm[ps], l1 = lsl[ps];
    float nm = fmaxf(m, m1);
    float s0 = exp2f(m - nm);
    float s1 = exp2f(m1 - nm);
    l = l * s0 + l1 * s1;
#pragma unroll
    for (int p = 0; p < P; ++p) acc[p] = acc[p] * s0 + lsacc[ps * P + p] * s1;
    m = nm;
  }

  float inv = 1.f / l;
  float y[P];
#pragma unroll
  for (int p = 0; p < P; ++p) y[p] = fmaf(acc[p], inv, bo[d0 + p]);

  // fused LayerNorm over the wave-held row
  float s = 0.f, s2 = 0.f;
#pragma unroll
  for (int p = 0; p < P; ++p) { s += y[p]; s2 = fmaf(y[p], y[p], s2); }
#pragma unroll
  for (int w = 1; w < 64; w <<= 1) {
    s += __shfl_xor(s, w, 64);
    s2 += __shfl_xor(s2, w, 64);
  }
  float mu = s * (1.f / D);
  float var = s2 * (1.f / D) - mu * mu;
  float rr = rsqrtf(var + 1e-5f);

  float z[P];
#pragma unroll
  for (int p = 0; p < P; ++p) {
    float v = (y[p] - mu) * rr * g[d0 + p] + bln[d0 + p];
    if (GELU_) v = 0.5f * v * (1.f + erff(v * 0.70710678118654752f));
    if (RES_) v += res[(size_t)n * D + d0 + p];
    z[p] = v;
  }
  if (WF32) {
    float* orow = outf + (size_t)n * D;
    if constexpr (P == 4) *(float4*)&orow[d0] = *(float4*)z;
    else                  *(float2*)&orow[d0] = *(float2*)z;
  }
  if (WBF16) {
    unsigned short* orow = outb + (size_t)n * D;
    if constexpr (P == 4) {
      ushort4 o; o.x = f2bf(z[0]); o.y = f2bf(z[1]); o.z = f2bf(z[2]); o.w = f2bf(z[3]);
      *(ushort4*)&orow[d0] = o;
    } else {
      ushort2 o; o.x = f2bf(z[0]); o.y = f2bf(z[1]);
      *(ushort2*)&orow[d0] = o;
    }
  }
  if (POOL) {
    int gr = batch[n];
    float wgt = ginv[gr];
#pragma unroll
    for (int p = 0; p < P; ++p)
      atomicAdd(&outp[gr * D + d0 + p], z[p] * wgt);
  }
}

// ============================ launch ============================

extern "C" void kernel_launch(void* const* d_in, const int* in_sizes, int n_in,
                              void* d_out, int out_size, void* d_ws, size_t ws_size,
                              hipStream_t stream) {
  const float* x   = (const float*)d_in[0];
  const int*   ei  = (const int*)d_in[1];
  const float* ea  = (const float*)d_in[2];
  const int*   bat = (const int*)d_in[3];
  // d_in[4] = num_graphs (256, hardcoded)
  const float* Wl1 = (const float*)d_in[5];  const float* bl1 = (const float*)d_in[6];
  const float* Wr1 = (const float*)d_in[7];  const float* br1 = (const float*)d_in[8];
  const float* We1 = (const float*)d_in[9];  const float* at1 = (const float*)d_in[10];
  const float* bo1 = (const float*)d_in[11];
  const float* Wl2 = (const float*)d_in[12]; const float* bl2 = (const float*)d_in[13];
  const float* Wr2 = (const float*)d_in[14]; const float* br2 = (const float*)d_in[15];
  const float* We2 = (const float*)d_in[16]; const float* at2 = (const float*)d_in[17];
  const float* bo2 = (const float*)d_in[18];
  const float* Wl3 = (const float*)d_in[19]; const float* bl3 = (const float*)d_in[20];
  const float* Wr3 = (const float*)d_in[21]; const float* br3 = (const float*)d_in[22];
  const float* We3 = (const float*)d_in[23]; const float* at3 = (const float*)d_in[24];
  const float* bo3 = (const float*)d_in[25];
  const float* g1 = (const float*)d_in[26]; const float* b1 = (const float*)d_in[27];
  const float* g2 = (const float*)d_in[28]; const float* b2 = (const float*)d_in[29];
  const float* g3 = (const float*)d_in[30]; const float* b3 = (const float*)d_in[31];
  const float* Wres = (const float*)d_in[32];
  float* out = (float*)d_out;

  char* ws = (char*)d_ws;
  size_t off = 0;
  // zero-init region: deg, easum (single memset)
  int*   deg    = (int*)(ws + off); off += NN * 4;
  float* easum  = (float*)(ws + off); off += NN * 4;
  size_t zero_bytes = off;
  unsigned short* xlb = (unsigned short*)(ws + off); off += (size_t)NN * DHID * 2;
  unsigned short* xrb = (unsigned short*)(ws + off); off += (size_t)NN * DHID * 2;
  float* hb   = (float*)(ws + off); off += (size_t)NN * DHID * 4;
  float* xres = (float*)(ws + off); off += (size_t)NN * DHID * 4;
  unsigned short* actb0 = (unsigned short*)(ws + off); off += (size_t)NN * KDIM1 * 2;
  unsigned short* actb1 = (unsigned short*)(ws + off); off += (size_t)NN * DHID * 2;
  int*   offs   = (int*)(ws + off); off += (NN + 1) * 4 + 60;
  int*   cursor = (int*)(ws + off); off += NN * 4;
  float* ginv   = (float*)(ws + off); off += NG * 4;
  int*   csr_src = (int*)(ws + off); off += (size_t)NE * 4;
  float* csr_ea  = (float*)(ws + off); off += (size_t)NE * 4;
  unsigned short* Wc1e = (unsigned short*)(ws + off); off += (size_t)3 * DHID * KDIM1 * 2;
  unsigned short* Wc2  = (unsigned short*)(ws + off); off += (size_t)2 * DHID * DHID * 2;
  unsigned short* Wc3  = (unsigned short*)(ws + off); off += (size_t)2 * DOUT3 * DHID * 2;

  // ---- zero-init + CSR build + prep ----
  hipMemsetAsync(deg, 0, zero_bytes, stream);
  hipMemsetAsync(out, 0, (size_t)NG * DOUT3 * 4, stream);   // pool accumulators
  k_edge_count<<<NE / 256, 256, 0, stream>>>(ei, ea, deg, easum);
  k_scan<<<1, 1024, 0, stream>>>(deg, easum, offs, cursor, bat, ginv);
  k_fill_csr<<<NE / 256, 256, 0, stream>>>(ei, ea, cursor, csr_src, csr_ea);
  k_prep<<<(PREP_TOTAL + 255) / 256, 256, 0, stream>>>(x, Wl1, Wr1, Wres, Wl2, Wr2, Wl3, Wr3,
                                                       actb0, Wc1e, Wc2, Wc3);

  dim3 blk(256);
  int gat_blocks = NN / 2;   // 2 waves per node, 4 waves per block

  // ---- layer 1: fused [Wl1|Wr1|Wres] GEMM, residual folded into gat epilogue ----
  gemm_lrr<<<dim3(3 * DHID / 128, NN / 128), blk, 0, stream>>>(
      (const short*)actb0, (const short*)Wc1e, bl1, br1, xlb, xrb, xres, KDIM1, DHID);
  gat_fused<DHID, 4, true, true, true, true, false><<<gat_blocks, blk, 0, stream>>>(
      xlb, xrb, We1, at1, bo1, offs, csr_src, csr_ea, easum, g1, b1, xres, hb, actb1,
      nullptr, nullptr, nullptr);

  // ---- layer 2 ----
  gemm_lr<<<dim3(2 * DHID / 128, NN / 128), blk, 0, stream>>>(
      (const short*)actb1, (const short*)Wc2, bl2, br2, xlb, xrb, DHID, DHID);
  gat_fused<DHID, 4, true, true, false, true, false><<<gat_blocks, blk, 0, stream>>>(
      xlb, xrb, We2, at2, bo2, offs, csr_src, csr_ea, easum, g2, b2, hb, nullptr, actb1,
      nullptr, nullptr, nullptr);

  // ---- layer 3: pool fused into gat epilogue ----
  gemm_lr<<<dim3(2 * DOUT3 / 128, NN / 128), blk, 0, stream>>>(
      (const short*)actb1, (const short*)Wc3, bl3, br3, xlb, xrb, DHID, DOUT3);
  gat_fused<DOUT3, 1, false, false, false, false, true><<<gat_blocks, blk, 0, stream>>>(
      xlb, xrb, We3, at3, bo3, offs, csr_src, csr_ea, easum, g3, b3, nullptr, nullptr, nullptr,
      bat, ginv, out);
}

// Round 18
// 220.374 us; speedup vs baseline: 1.1889x; 1.1889x over previous
//
#include <hip/hip_runtime.h>
#include <hip/hip_bf16.h>
#include <math.h>

#define NN 16384     // nodes
#define NE 262144    // edges
#define KDIM1 480
#define DHID 256
#define DOUT3 128
#define NG 256       // graphs

typedef short bf16x8 __attribute__((ext_vector_type(8)));
typedef float f32x4 __attribute__((ext_vector_type(4)));

#define LOG2E 1.44269504088896340736f

__device__ __forceinline__ unsigned short f2bf(float f) {
  unsigned u = __float_as_uint(f);
  unsigned r = (u + 0x7fffu + ((u >> 16) & 1u)) >> 16;
  return (unsigned short)r;
}
__device__ __forceinline__ float bf2f(unsigned short u) {
  return __uint_as_float((unsigned)u << 16);
}

__device__ __forceinline__ void gload_lds16(const void* g, void* l) {
  __builtin_amdgcn_global_load_lds((const __attribute__((address_space(1))) void*)g,
                                   (__attribute__((address_space(3))) void*)l,
                                   16, 0, 0);
}

__device__ __forceinline__ int lower_bound_i(const int* arr, int n, int val) {
  int lo = 0, hi = n;
  while (lo < hi) {
    int mid = (lo + hi) >> 1;
    if (arr[mid] < val) lo = mid + 1; else hi = mid;
  }
  return lo;
}

// ============================ merged edge-count + prep ============================
// seg_ec: edge histogram (atomics); seg0: x->bf16; seg1: Wc1e=[Wl1|Wr1|Wres];
// seg2: Wc2; seg3: Wc3. All segments independent; consumed by later kernels.

#define PREP_S0 (NN * KDIM1 / 4)
#define PREP_S1 (3 * DHID * KDIM1)
#define PREP_S2 (2 * DHID * DHID)
#define PREP_S3 (2 * DOUT3 * DHID)
#define PREP_TOTAL (NE + PREP_S0 + PREP_S1 + PREP_S2 + PREP_S3)

__global__ __launch_bounds__(256) void k_prep_ec(
    const int* __restrict__ ei, const float* __restrict__ ea,
    int* __restrict__ deg, float* __restrict__ easum,
    const float* __restrict__ x,
    const float* __restrict__ Wl1, const float* __restrict__ Wr1,
    const float* __restrict__ Wres,
    const float* __restrict__ Wl2, const float* __restrict__ Wr2,
    const float* __restrict__ Wl3, const float* __restrict__ Wr3,
    unsigned short* __restrict__ actb0, unsigned short* __restrict__ Wc1e,
    unsigned short* __restrict__ Wc2, unsigned short* __restrict__ Wc3) {
  int idx = blockIdx.x * 256 + threadIdx.x;
  if (idx < NE) {
    int d = ei[NE + idx];
    atomicAdd(&deg[d], 1);
    atomicAdd(&easum[d], ea[idx]);
    return;
  }
  idx -= NE;
  if (idx < PREP_S0) {
    int i = idx * 4;
    float4 v = *(const float4*)&x[i];
    ushort4 o;
    o.x = f2bf(v.x); o.y = f2bf(v.y); o.z = f2bf(v.z); o.w = f2bf(v.w);
    *(ushort4*)&actb0[i] = o;
    return;
  }
  idx -= PREP_S0;
  if (idx < PREP_S1) {
    int n = idx / KDIM1, k = idx % KDIM1;
    float v;
    if (n < DHID)            v = Wl1[(size_t)k * DHID + n];
    else if (n < 2 * DHID)   v = Wr1[(size_t)k * DHID + (n - DHID)];
    else                     v = Wres[(size_t)k * DHID + (n - 2 * DHID)];
    Wc1e[idx] = f2bf(v);
    return;
  }
  idx -= PREP_S1;
  if (idx < PREP_S2) {
    int n = idx / DHID, k = idx % DHID;
    float v = (n < DHID) ? Wl2[(size_t)k * DHID + n] : Wr2[(size_t)k * DHID + (n - DHID)];
    Wc2[idx] = f2bf(v);
    return;
  }
  idx -= PREP_S2;
  if (idx < PREP_S3) {
    int n = idx / DHID, k = idx % DHID;
    float v = (n < DOUT3) ? Wl3[(size_t)k * DOUT3 + n] : Wr3[(size_t)k * DOUT3 + (n - DOUT3)];
    Wc3[idx] = f2bf(v);
  }
}

// scan + loop_ea finalize + per-graph inverse counts (threads t<NG)
__global__ __launch_bounds__(1024) void k_scan(const int* __restrict__ deg,
                                               float* __restrict__ easum,
                                               int* __restrict__ offs,
                                               int* __restrict__ cursor,
                                               const int* __restrict__ bat,
                                               float* __restrict__ ginv) {
  __shared__ int sums[1024];
  int t = threadIdx.x;
  int base = t * 16;
  int local[16];
  int s = 0;
#pragma unroll
  for (int i = 0; i < 16; ++i) { local[i] = deg[base + i]; s += local[i]; }
  sums[t] = s;
  __syncthreads();
  for (int d = 1; d < 1024; d <<= 1) {
    int v = (t >= d) ? sums[t - d] : 0;
    __syncthreads();
    sums[t] += v;
    __syncthreads();
  }
  int prefix = (t == 0) ? 0 : sums[t - 1];
#pragma unroll
  for (int i = 0; i < 16; ++i) {
    offs[base + i] = prefix;
    cursor[base + i] = prefix;
    prefix += local[i];
  }
  if (t == 1023) offs[NN] = prefix;
#pragma unroll
  for (int i = 0; i < 16; ++i) {
    easum[base + i] = easum[base + i] / fmaxf((float)local[i], 1.f);
  }
  if (t < NG) {
    int lo = lower_bound_i(bat, NN, t);
    int hi = lower_bound_i(bat, NN, t + 1);
    ginv[t] = 1.f / fmaxf((float)(hi - lo), 1.f);
  }
}

__global__ __launch_bounds__(256) void k_fill_csr(const int* __restrict__ ei,
                                                  const float* __restrict__ ea,
                                                  int* __restrict__ cursor,
                                                  int* __restrict__ csr_src,
                                                  float* __restrict__ csr_ea) {
  int e = blockIdx.x * 256 + threadIdx.x;
  if (e >= NE) return;
  int s = ei[e];
  int d = ei[NE + e];
  int pos = atomicAdd(&cursor[d], 1);
  csr_src[pos] = s;
  csr_ea[pos] = ea[e];
}

// ============================ bf16 MFMA GEMM cores ============================
// 128x128 tile, BK=32, 4 waves (2x2), each wave 64x64 = 4x4 16x16 frags.

#define GEMM_CORE128(A_, Bt_, K_)                                                \
  __shared__ short As[128 * 32];                                                 \
  __shared__ short Bs[128 * 32];                                                 \
  int t = threadIdx.x;                                                           \
  int w = t >> 6;                                                                \
  int lane = t & 63;                                                             \
  int bm = blockIdx.y * 128;                                                     \
  int bn = blockIdx.x * 128;                                                     \
  int wr = w >> 1, wc = w & 1;                                                   \
  const short* Ag0 = A_ + (size_t)(bm + w * 16 + (lane >> 2)) * K_ + (lane & 3) * 8;        \
  const short* Ag1 = A_ + (size_t)(bm + 64 + w * 16 + (lane >> 2)) * K_ + (lane & 3) * 8;   \
  const short* Bg0 = Bt_ + (size_t)(bn + w * 16 + (lane >> 2)) * K_ + (lane & 3) * 8;       \
  const short* Bg1 = Bt_ + (size_t)(bn + 64 + w * 16 + (lane >> 2)) * K_ + (lane & 3) * 8;  \
  short* Al0 = &As[w * 16 * 32];                                                 \
  short* Al1 = &As[(64 + w * 16) * 32];                                          \
  short* Bl0 = &Bs[w * 16 * 32];                                                 \
  short* Bl1 = &Bs[(64 + w * 16) * 32];                                          \
  f32x4 acc[4][4] = {};                                                          \
  for (int k0 = 0; k0 < K_; k0 += 32) {                                          \
    gload_lds16(Ag0, Al0);                                                       \
    gload_lds16(Ag1, Al1);                                                       \
    gload_lds16(Bg0, Bl0);                                                       \
    gload_lds16(Bg1, Bl1);                                                       \
    Ag0 += 32; Ag1 += 32; Bg0 += 32; Bg1 += 32;                                  \
    __syncthreads();                                                             \
    bf16x8 af[4], bfv[4];                                                        \
    _Pragma("unroll")                                                            \
    for (int mi = 0; mi < 4; ++mi)                                               \
      af[mi] = *(const bf16x8*)&As[(wr * 64 + mi * 16 + (lane & 15)) * 32 + (lane >> 4) * 8]; \
    _Pragma("unroll")                                                            \
    for (int ni = 0; ni < 4; ++ni)                                               \
      bfv[ni] = *(const bf16x8*)&Bs[(wc * 64 + ni * 16 + (lane & 15)) * 32 + (lane >> 4) * 8]; \
    _Pragma("unroll")                                                            \
    for (int mi = 0; mi < 4; ++mi)                                               \
      _Pragma("unroll")                                                          \
      for (int ni = 0; ni < 4; ++ni)                                             \
        acc[mi][ni] = __builtin_amdgcn_mfma_f32_16x16x32_bf16(af[mi], bfv[ni], acc[mi][ni], 0, 0, 0); \
    __syncthreads();                                                             \
  }                                                                              \
  int col = lane & 15;                                                           \
  int row4 = (lane >> 4) * 4;

// Layer-1 triple: n<NH -> xlb(+bl); n<2NH -> xrb(+br); else -> xres (f32, no bias).
// grid.x = 3*NH/128.
__global__ __launch_bounds__(256) void gemm_lrr(const short* __restrict__ A,
                                                const short* __restrict__ Wt,
                                                const float* __restrict__ bl,
                                                const float* __restrict__ br,
                                                unsigned short* __restrict__ xlb,
                                                unsigned short* __restrict__ xrb,
                                                float* __restrict__ xres,
                                                int K, int NH) {
  GEMM_CORE128(A, Wt, K)
  int seg = bn / NH;            // 0,1,2 (tile never straddles: NH%128==0)
  int cbase = bn - seg * NH;
#pragma unroll
  for (int mi = 0; mi < 4; ++mi) {
#pragma unroll
    for (int ni = 0; ni < 4; ++ni) {
      f32x4 a = acc[mi][ni];
      int gc = cbase + wc * 64 + ni * 16 + col;
      if (seg == 2) {
#pragma unroll
        for (int r = 0; r < 4; ++r) {
          int gr = bm + wr * 64 + mi * 16 + row4 + r;
          xres[(size_t)gr * NH + gc] = a[r];
        }
      } else {
        const float* bias = seg ? br : bl;
        unsigned short* outp = seg ? xrb : xlb;
        float bv = bias[gc];
#pragma unroll
        for (int r = 0; r < 4; ++r) {
          int gr = bm + wr * 64 + mi * 16 + row4 + r;
          outp[(size_t)gr * NH + gc] = f2bf(a[r] + bv);
        }
      }
    }
  }
}

// C left/right split, bf16 outputs. grid.x = 2*NH/128 (NH%128==0).
__global__ __launch_bounds__(256) void gemm_lr(const short* __restrict__ A,
                                               const short* __restrict__ Wt,
                                               const float* __restrict__ bl,
                                               const float* __restrict__ br,
                                               unsigned short* __restrict__ xlb,
                                               unsigned short* __restrict__ xrb,
                                               int K, int NH) {
  GEMM_CORE128(A, Wt, K)
  bool right = (bn >= NH);
  unsigned short* outp = right ? xrb : xlb;
  const float* bias = right ? br : bl;
  int cbase = right ? bn - NH : bn;
#pragma unroll
  for (int mi = 0; mi < 4; ++mi) {
#pragma unroll
    for (int ni = 0; ni < 4; ++ni) {
      f32x4 a = acc[mi][ni];
      int gc = cbase + wc * 64 + ni * 16 + col;
      float bv = bias[gc];
#pragma unroll
      for (int r = 0; r < 4; ++r) {
        int gr = bm + wr * 64 + mi * 16 + row4 + r;
        outp[(size_t)gr * NH + gc] = f2bf(a[r] + bv);
      }
    }
  }
}

// ============================ fused GATv2 + LN (+GELU) (+RES) (+POOL) ============================
// r15-proven form: static one-wave-per-node; bf16 gather; exp2-domain online
// softmax; 4-edge unrolled loop. (r13 atomic-balance, r16 8-deep ILP, r17
// wave-split all measured slower — do not restructure.)

template<int D, int H, bool GELU_, bool RES_, bool WF32, bool WBF16, bool POOL>
__global__ __launch_bounds__(256) void gat_fused(
    const unsigned short* __restrict__ xlb, const unsigned short* __restrict__ xrb,
    const float* __restrict__ We, const float* __restrict__ att,
    const float* __restrict__ bo,
    const int* __restrict__ offs, const int* __restrict__ csr_src,
    const float* __restrict__ csr_ea, const float* __restrict__ loop_ea,
    const float* __restrict__ g, const float* __restrict__ bln,
    const float* __restrict__ res,
    float* __restrict__ outf, unsigned short* __restrict__ outb,
    const int* __restrict__ batch, const float* __restrict__ ginv,
    float* __restrict__ outp) {
  constexpr int P = D / 64;
  constexpr int C = D / H;
  constexpr int GROUP = C / P;   // lanes per head
  int n = (blockIdx.x * blockDim.x + threadIdx.x) >> 6;
  int lane = threadIdx.x & 63;
  if (n >= NN) return;
  int d0 = lane * P;

  float wev[P], attv[P], xrv[P];
  if constexpr (P == 4) {
    *(float4*)wev = *(const float4*)&We[d0];
    *(float4*)attv = *(const float4*)&att[d0];
    ushort4 u = *(const ushort4*)&xrb[(size_t)n * D + d0];
    xrv[0] = bf2f(u.x); xrv[1] = bf2f(u.y); xrv[2] = bf2f(u.z); xrv[3] = bf2f(u.w);
  } else {
    *(float2*)wev = *(const float2*)&We[d0];
    *(float2*)attv = *(const float2*)&att[d0];
    ushort2 u = *(const ushort2*)&xrb[(size_t)n * D + d0];
    xrv[0] = bf2f(u.x); xrv[1] = bf2f(u.y);
  }
#pragma unroll
  for (int p = 0; p < P; ++p) attv[p] *= LOG2E;   // exp2 domain (monotone)

#define GATHER(dst, srcidx)                                                  \
  {                                                                          \
    if constexpr (P == 4) {                                                  \
      ushort4 u_ = *(const ushort4*)&xlb[(size_t)(srcidx) * D + d0];         \
      dst[0] = bf2f(u_.x); dst[1] = bf2f(u_.y);                              \
      dst[2] = bf2f(u_.z); dst[3] = bf2f(u_.w);                              \
    } else {                                                                 \
      ushort2 u_ = *(const ushort2*)&xlb[(size_t)(srcidx) * D + d0];         \
      dst[0] = bf2f(u_.x); dst[1] = bf2f(u_.y);                              \
    }                                                                        \
  }

#define ALPHA(out_, xv_, eav_)                                               \
  {                                                                          \
    float partial_ = 0.f;                                                    \
    _Pragma("unroll")                                                        \
    for (int p = 0; p < P; ++p) {                                            \
      float s_ = xv_[p] + xrv[p] + (eav_) * wev[p];                          \
      s_ = fmaxf(s_, 0.2f * s_);                                             \
      partial_ = fmaf(s_, attv[p], partial_);                                \
    }                                                                        \
    _Pragma("unroll")                                                        \
    for (int w_ = 1; w_ < GROUP; w_ <<= 1) partial_ += __shfl_xor(partial_, w_, 64); \
    out_ = partial_;                                                         \
  }

  // ---- self-loop prologue: m = alpha_self, l = 1, acc = xv_self ----
  float acc[P];
  float xs[P];
  GATHER(xs, n)
  float m;
  ALPHA(m, xs, loop_ea[n])
  float l = 1.f;
#pragma unroll
  for (int p = 0; p < P; ++p) acc[p] = xs[p];

  int beg = offs[n];
  int cnt = offs[n + 1] - beg;
  int sbeg = __builtin_amdgcn_readfirstlane(beg);
  int scnt = __builtin_amdgcn_readfirstlane(cnt);

  int e = 0;
  for (; e + 4 <= scnt; e += 4) {
    int s0 = csr_src[sbeg + e];
    int s1 = csr_src[sbeg + e + 1];
    int s2 = csr_src[sbeg + e + 2];
    int s3 = csr_src[sbeg + e + 3];
    float ea0 = csr_ea[sbeg + e];
    float ea1 = csr_ea[sbeg + e + 1];
    float ea2 = csr_ea[sbeg + e + 2];
    float ea3 = csr_ea[sbeg + e + 3];
    float xv0[P], xv1[P], xv2[P], xv3[P];
    GATHER(xv0, s0)
    GATHER(xv1, s1)
    GATHER(xv2, s2)
    GATHER(xv3, s3)
    float a0, a1, a2, a3;
    ALPHA(a0, xv0, ea0)
    ALPHA(a1, xv1, ea1)
    ALPHA(a2, xv2, ea2)
    ALPHA(a3, xv3, ea3)
    float nm = fmaxf(fmaxf(m, fmaxf(a0, a1)), fmaxf(a2, a3));
    float sc = exp2f(m - nm);
    float pe0 = exp2f(a0 - nm);
    float pe1 = exp2f(a1 - nm);
    float pe2 = exp2f(a2 - nm);
    float pe3 = exp2f(a3 - nm);
    l = fmaf(l, sc, (pe0 + pe1) + (pe2 + pe3));
#pragma unroll
    for (int p = 0; p < P; ++p)
      acc[p] = fmaf(acc[p], sc,
                    fmaf(pe0, xv0[p], fmaf(pe1, xv1[p], fmaf(pe2, xv2[p], pe3 * xv3[p]))));
    m = nm;
  }
  for (; e < scnt; ++e) {
    int s0 = csr_src[sbeg + e];
    float ea0 = csr_ea[sbeg + e];
    float xv0[P];
    GATHER(xv0, s0)
    float a0;
    ALPHA(a0, xv0, ea0)
    float nm = fmaxf(m, a0);
    float sc = exp2f(m - nm);
    float pe0 = exp2f(a0 - nm);
    l = fmaf(l, sc, pe0);
#pragma unroll
    for (int p = 0; p < P; ++p) acc[p] = fmaf(acc[p], sc, pe0 * xv0[p]);
    m = nm;
  }
#undef GATHER
#undef ALPHA

  float inv = 1.f / l;
  float y[P];
#pragma unroll
  for (int p = 0; p < P; ++p) y[p] = fmaf(acc[p], inv, bo[d0 + p]);

  // fused LayerNorm over the wave-held row
  float s = 0.f, s2 = 0.f;
#pragma unroll
  for (int p = 0; p < P; ++p) { s += y[p]; s2 = fmaf(y[p], y[p], s2); }
#pragma unroll
  for (int w = 1; w < 64; w <<= 1) {
    s += __shfl_xor(s, w, 64);
    s2 += __shfl_xor(s2, w, 64);
  }
  float mu = s * (1.f / D);
  float var = s2 * (1.f / D) - mu * mu;
  float rr = rsqrtf(var + 1e-5f);

  float z[P];
#pragma unroll
  for (int p = 0; p < P; ++p) {
    float v = (y[p] - mu) * rr * g[d0 + p] + bln[d0 + p];
    if (GELU_) v = 0.5f * v * (1.f + erff(v * 0.70710678118654752f));
    if (RES_) v += res[(size_t)n * D + d0 + p];
    z[p] = v;
  }
  if (WF32) {
    float* orow = outf + (size_t)n * D;
    if constexpr (P == 4) *(float4*)&orow[d0] = *(float4*)z;
    else                  *(float2*)&orow[d0] = *(float2*)z;
  }
  if (WBF16) {
    unsigned short* orow = outb + (size_t)n * D;
    if constexpr (P == 4) {
      ushort4 o; o.x = f2bf(z[0]); o.y = f2bf(z[1]); o.z = f2bf(z[2]); o.w = f2bf(z[3]);
      *(ushort4*)&orow[d0] = o;
    } else {
      ushort2 o; o.x = f2bf(z[0]); o.y = f2bf(z[1]);
      *(ushort2*)&orow[d0] = o;
    }
  }
  if (POOL) {
    int gr = batch[n];
    float wgt = ginv[gr];
#pragma unroll
    for (int p = 0; p < P; ++p)
      atomicAdd(&outp[gr * D + d0 + p], z[p] * wgt);
  }
}

// ============================ launch ============================

extern "C" void kernel_launch(void* const* d_in, const int* in_sizes, int n_in,
                              void* d_out, int out_size, void* d_ws, size_t ws_size,
                              hipStream_t stream) {
  const float* x   = (const float*)d_in[0];
  const int*   ei  = (const int*)d_in[1];
  const float* ea  = (const float*)d_in[2];
  const int*   bat = (const int*)d_in[3];
  // d_in[4] = num_graphs (256, hardcoded)
  const float* Wl1 = (const float*)d_in[5];  const float* bl1 = (const float*)d_in[6];
  const float* Wr1 = (const float*)d_in[7];  const float* br1 = (const float*)d_in[8];
  const float* We1 = (const float*)d_in[9];  const float* at1 = (const float*)d_in[10];
  const float* bo1 = (const float*)d_in[11];
  const float* Wl2 = (const float*)d_in[12]; const float* bl2 = (const float*)d_in[13];
  const float* Wr2 = (const float*)d_in[14]; const float* br2 = (const float*)d_in[15];
  const float* We2 = (const float*)d_in[16]; const float* at2 = (const float*)d_in[17];
  const float* bo2 = (const float*)d_in[18];
  const float* Wl3 = (const float*)d_in[19]; const float* bl3 = (const float*)d_in[20];
  const float* Wr3 = (const float*)d_in[21]; const float* br3 = (const float*)d_in[22];
  const float* We3 = (const float*)d_in[23]; const float* at3 = (const float*)d_in[24];
  const float* bo3 = (const float*)d_in[25];
  const float* g1 = (const float*)d_in[26]; const float* b1 = (const float*)d_in[27];
  const float* g2 = (const float*)d_in[28]; const float* b2 = (const float*)d_in[29];
  const float* g3 = (const float*)d_in[30]; const float* b3 = (const float*)d_in[31];
  const float* Wres = (const float*)d_in[32];
  float* out = (float*)d_out;

  char* ws = (char*)d_ws;
  size_t off = 0;
  // zero-init region: deg, easum (single memset)
  int*   deg    = (int*)(ws + off); off += NN * 4;
  float* easum  = (float*)(ws + off); off += NN * 4;
  size_t zero_bytes = off;
  unsigned short* xlb = (unsigned short*)(ws + off); off += (size_t)NN * DHID * 2;
  unsigned short* xrb = (unsigned short*)(ws + off); off += (size_t)NN * DHID * 2;
  float* hb   = (float*)(ws + off); off += (size_t)NN * DHID * 4;
  float* xres = (float*)(ws + off); off += (size_t)NN * DHID * 4;
  unsigned short* actb0 = (unsigned short*)(ws + off); off += (size_t)NN * KDIM1 * 2;
  unsigned short* actb1 = (unsigned short*)(ws + off); off += (size_t)NN * DHID * 2;
  int*   offs   = (int*)(ws + off); off += (NN + 1) * 4 + 60;
  int*   cursor = (int*)(ws + off); off += NN * 4;
  float* ginv   = (float*)(ws + off); off += NG * 4;
  int*   csr_src = (int*)(ws + off); off += (size_t)NE * 4;
  float* csr_ea  = (float*)(ws + off); off += (size_t)NE * 4;
  unsigned short* Wc1e = (unsigned short*)(ws + off); off += (size_t)3 * DHID * KDIM1 * 2;
  unsigned short* Wc2  = (unsigned short*)(ws + off); off += (size_t)2 * DHID * DHID * 2;
  unsigned short* Wc3  = (unsigned short*)(ws + off); off += (size_t)2 * DOUT3 * DHID * 2;

  // ---- zero-init + merged edge-count/prep + CSR ----
  hipMemsetAsync(deg, 0, zero_bytes, stream);
  hipMemsetAsync(out, 0, (size_t)NG * DOUT3 * 4, stream);   // pool accumulators
  k_prep_ec<<<(PREP_TOTAL + 255) / 256, 256, 0, stream>>>(
      ei, ea, deg, easum, x, Wl1, Wr1, Wres, Wl2, Wr2, Wl3, Wr3,
      actb0, Wc1e, Wc2, Wc3);
  k_scan<<<1, 1024, 0, stream>>>(deg, easum, offs, cursor, bat, ginv);
  k_fill_csr<<<NE / 256, 256, 0, stream>>>(ei, ea, cursor, csr_src, csr_ea);

  dim3 blk(256);
  int nwave_blocks = NN / 4;   // static: one wave per node

  // ---- layer 1: fused [Wl1|Wr1|Wres] GEMM, residual folded into gat epilogue ----
  gemm_lrr<<<dim3(3 * DHID / 128, NN / 128), blk, 0, stream>>>(
      (const short*)actb0, (const short*)Wc1e, bl1, br1, xlb, xrb, xres, KDIM1, DHID);
  gat_fused<DHID, 4, true, true, true, true, false><<<nwave_blocks, blk, 0, stream>>>(
      xlb, xrb, We1, at1, bo1, offs, csr_src, csr_ea, easum, g1, b1, xres, hb, actb1,
      nullptr, nullptr, nullptr);

  // ---- layer 2 ----
  gemm_lr<<<dim3(2 * DHID / 128, NN / 128), blk, 0, stream>>>(
      (const short*)actb1, (const short*)Wc2, bl2, br2, xlb, xrb, DHID, DHID);
  gat_fused<DHID, 4, true, true, false, true, false><<<nwave_blocks, blk, 0, stream>>>(
      xlb, xrb, We2, at2, bo2, offs, csr_src, csr_ea, easum, g2, b2, hb, nullptr, actb1,
      nullptr, nullptr, nullptr);

  // ---- layer 3: pool fused into gat epilogue ----
  gemm_lr<<<dim3(2 * DOUT3 / 128, NN / 128), blk, 0, stream>>>(
      (const short*)actb1, (const short*)Wc3, bl3, br3, xlb, xrb, DHID, DOUT3);
  gat_fused<DOUT3, 1, false, false, false, false, true><<<nwave_blocks, blk, 0, stream>>>(
      xlb, xrb, We3, at3, bo3, offs, csr_src, csr_ea, easum, g3, b3, nullptr, nullptr, nullptr,
      bat, ginv, out);
}